// Round 4
// baseline (168.793 us; speedup 1.0000x reference)
//
#include <hip/hip_runtime.h>
#include <hip/hip_bf16.h>

#define LD 65  // LDS row stride in floats (64 + 1 pad)

__global__ __launch_bounds__(256) void lagat_kernel(
    const float* __restrict__ adj,
    const float* __restrict__ feat_node,
    const int* __restrict__ idx,
    const int* __restrict__ head_ids,
    const int* __restrict__ tail_ids,
    const float* __restrict__ transform,
    const float* __restrict__ embed,
    const float* __restrict__ w1, const float* __restrict__ b1,
    const float* __restrict__ w2, const float* __restrict__ b2,
    const float* __restrict__ gamma1, const float* __restrict__ beta1,
    const float* __restrict__ gamma2, const float* __restrict__ beta2,
    float* __restrict__ out)
{
  __shared__ float Ab[64][LD];      // adjacency block (0/1 floats)
  __shared__ float featb[64][LD];   // transformed features
  __shared__ float Sb[2][64][LD];   // [0]=all_feat_head, [1]=all_feat_tail
  __shared__ float Xb[2][64][LD];   // scratch (init_feat, then per-chain x)
  __shared__ float reach[2][3][64]; // BFS reach indicators (0/1 floats)
  __shared__ float degs[64];
  __shared__ float corr[2][64];
  __shared__ float mus[2][64], rstds[2][64];

  const int g = blockIdx.x;
  const int tid = threadIdx.x;
  const int nb = g * 64;

  // ---- load adjacency block; build init_feat = [feat_node | embed[idx]] ----
  {
    const int r = tid >> 2, c0 = (tid & 3) * 16;
    for (int c = 0; c < 16; ++c)
      Ab[r][c0 + c] = adj[(size_t)(nb + r) * 4096 + (size_t)nb + c0 + c];
    for (int c = 0; c < 16; ++c) {
      const int cc = c0 + c;
      Xb[0][r][cc] = (cc < 32)
          ? feat_node[(size_t)(nb + r) * 32 + cc]
          : embed[(size_t)idx[nb + r] * 32 + (cc - 32)];
    }
  }
  __syncthreads();

  const int hl = head_ids[g] - nb;  // local head (=0) and tail (=1) ids
  const int tl = tail_ids[g] - nb;

  // ---- degrees; BFS reach levels 0 and 1 ----
  if (tid < 64) {
    float s = 0.0f;
    for (int k = 0; k < 64; ++k) s += Ab[tid][k];
    degs[tid] = s;
  } else if (tid >= 128) {
    const int ch = (tid - 128) >> 6, j = tid & 63;
    const int root = ch ? tl : hl;
    reach[ch][0][j] = (j == root) ? 1.0f : 0.0f;
    reach[ch][1][j] = (j == root || Ab[root][j] != 0.0f) ? 1.0f : 0.0f;
  }
  __syncthreads();

  // ---- reach level 2: root U { j : exists k in level1 with A[k][j] } ----
  if (tid < 128) {
    const int ch = tid >> 6, j = tid & 63;
    const int root = ch ? tl : hl;
    float v = (j == root) ? 1.0f : 0.0f;
    for (int k = 0; k < 64; ++k)
      if (reach[ch][1][k] != 0.0f && Ab[k][j] != 0.0f) v = 1.0f;
    reach[ch][2][j] = v;
  }
  // ---- feat = init_feat @ transform (runs on all threads concurrently) ----
  {
    const int r = tid >> 2, c0 = (tid & 3) * 16;
    float acc[16];
    for (int c = 0; c < 16; ++c) acc[c] = 0.0f;
    for (int k = 0; k < 64; ++k) {
      const float a = Xb[0][r][k];
      for (int c = 0; c < 16; ++c)
        acc[c] = fmaf(a, transform[(size_t)k * 64 + c0 + c], acc[c]);
    }
    for (int c = 0; c < 16; ++c) featb[r][c0 + c] = acc[c];
  }
  __syncthreads();

  // ---- init states; write layer 0 = feat ----
  {
    const int r = tid >> 2, c0 = (tid & 3) * 16;
    for (int c = 0; c < 16; ++c) {
      const float v = featb[r][c0 + c];
      Sb[0][r][c0 + c] = v;
      Sb[1][r][c0 + c] = v;
      out[(size_t)(nb + r) * 256 + c0 + c] = v;
    }
  }
  __syncthreads();

  for (int hop = 2; hop >= 0; --hop) {
    // A: corr[ch][i] = |dot(query, S[ch][i])|  (head chain uses tail query)
    if (tid < 128) {
      const int ch = tid >> 6, i = tid & 63;
      const int qrow = ch ? hl : tl;
      float s = 0.0f;
      for (int l = 0; l < 64; ++l) s = fmaf(featb[qrow][l], Sb[ch][i][l], s);
      corr[ch][i] = fabsf(s);
    }
    __syncthreads();
    // B: x[i][c] = leaky(sum_j A[i][j]*corr[j]*S[j][c]) / (deg[i]+1e-8)
    {
      const int ch = tid >> 7, t = tid & 127;
      const int i = t >> 1, c0 = (t & 1) * 32;
      float acc[32];
      for (int c = 0; c < 32; ++c) acc[c] = 0.0f;
      for (int j = 0; j < 64; ++j) {
        if (Ab[i][j] != 0.0f) {
          const float cj = corr[ch][j];
          for (int c = 0; c < 32; ++c)
            acc[c] = fmaf(cj, Sb[ch][j][c0 + c], acc[c]);
        }
      }
      const float dn = 1.0f / (degs[i] + 1e-8f);
      for (int c = 0; c < 32; ++c) {
        float z = acc[c];
        z = (z > 0.0f) ? z : 0.01f * z;   // leaky_relu slope 0.01
        Xb[ch][i][c0 + c] = z * dn;
      }
    }
    __syncthreads();
    // C: LayerNorm row stats (two-pass, biased variance)
    if (tid < 128) {
      const int ch = tid >> 6, i = tid & 63;
      float s = 0.0f;
      for (int l = 0; l < 64; ++l) s += Xb[ch][i][l];
      const float mu = s * 0.015625f;
      float v = 0.0f;
      for (int l = 0; l < 64; ++l) {
        const float d = Xb[ch][i][l] - mu;
        v = fmaf(d, d, v);
      }
      mus[ch][i] = mu;
      rstds[ch][i] = rsqrtf(v * 0.015625f + 1e-5f);
    }
    __syncthreads();
    // D: X = f*feat + gamma*(x-mu)*rstd + beta
    {
      const int ch = tid >> 7, t = tid & 127;
      const int i = t >> 1, c0 = (t & 1) * 32;
      const float f = reach[ch][hop][i];
      const float mu = mus[ch][i], rs = rstds[ch][i];
      const float* __restrict__ ga = ch ? gamma2 : gamma1;
      const float* __restrict__ be = ch ? beta2 : beta1;
      for (int c = 0; c < 32; ++c) {
        const int cc = c0 + c;
        const float x = Xb[ch][i][cc];
        Xb[ch][i][cc] = fmaf(f, featb[i][cc], ga[cc] * (x - mu) * rs + be[cc]);
      }
    }
    __syncthreads();
    // E: S[i] = f ? relu(X[i] @ W + b) : S[i]
    {
      const int ch = tid >> 7, t = tid & 127;
      const int i = t >> 1, c0 = (t & 1) * 32;
      const float* __restrict__ W = ch ? w2 : w1;
      const float* __restrict__ bb = ch ? b2 : b1;
      float acc[32];
      for (int c = 0; c < 32; ++c) acc[c] = bb[c0 + c];
      for (int k = 0; k < 64; ++k) {
        const float xv = Xb[ch][i][k];
        for (int c = 0; c < 32; ++c)
          acc[c] = fmaf(xv, W[(size_t)k * 64 + c0 + c], acc[c]);
      }
      if (reach[ch][hop][i] != 0.0f) {
        for (int c = 0; c < 32; ++c)
          Sb[ch][i][c0 + c] = fmaxf(acc[c], 0.0f);
      }
    }
    __syncthreads();
    // F: layer output L = 3-hop : out = H + T (float32!)
    {
      const int L = 3 - hop;
      const int r = tid >> 2, c0 = (tid & 3) * 16;
      for (int c = 0; c < 16; ++c)
        out[(size_t)(nb + r) * 256 + (size_t)L * 64 + c0 + c] =
            Sb[0][r][c0 + c] + Sb[1][r][c0 + c];
    }
    __syncthreads();
  }
}

extern "C" void kernel_launch(void* const* d_in, const int* in_sizes, int n_in,
                              void* d_out, int out_size, void* d_ws, size_t ws_size,
                              hipStream_t stream) {
  const float* adj       = (const float*)d_in[0];
  const float* feat_node = (const float*)d_in[1];
  const int*   idx       = (const int*)d_in[2];
  const int*   head_ids  = (const int*)d_in[3];
  const int*   tail_ids  = (const int*)d_in[4];
  // d_in[5] = graph_indices (implied by block structure, unused)
  const float* transform = (const float*)d_in[6];
  const float* embed     = (const float*)d_in[7];
  const float* w1     = (const float*)d_in[8];
  const float* b1     = (const float*)d_in[9];
  const float* w2     = (const float*)d_in[10];
  const float* b2     = (const float*)d_in[11];
  const float* gamma1 = (const float*)d_in[12];
  const float* beta1  = (const float*)d_in[13];
  const float* gamma2 = (const float*)d_in[14];
  const float* beta2  = (const float*)d_in[15];

  lagat_kernel<<<64, 256, 0, stream>>>(adj, feat_node, idx, head_ids, tail_ids,
      transform, embed, w1, b1, w2, b2, gamma1, beta1, gamma2, beta2,
      (float*)d_out);
}

// Round 5
// 52.280 us; speedup vs baseline: 3.2287x; 3.2287x over previous
//
#include <hip/hip_runtime.h>

#define LD 68  // LDS row stride in floats: 272B = 17x16B, 16B-aligned rows

__global__ __launch_bounds__(512) void lagat_kernel(
    const float* __restrict__ adj,
    const float* __restrict__ feat_node,
    const int* __restrict__ idx,
    const int* __restrict__ head_ids,
    const int* __restrict__ tail_ids,
    const float* __restrict__ transform,
    const float* __restrict__ embed,
    const float* __restrict__ w1, const float* __restrict__ b1,
    const float* __restrict__ w2, const float* __restrict__ b2,
    const float* __restrict__ gamma1, const float* __restrict__ beta1,
    const float* __restrict__ gamma2, const float* __restrict__ beta2,
    float* __restrict__ out)
{
  __shared__ __align__(16) float Ab[64][LD];     // adjacency (0/1)
  __shared__ __align__(16) float featb[64][LD];  // transformed features
  __shared__ __align__(16) float Sb[2][64][LD];  // head/tail running state
  __shared__ __align__(16) float Xb[2][64][LD];  // init_feat, then X scratch
  __shared__ __align__(16) float Wb[2][4096];    // w1, w2 staged
  __shared__ float prm[2][3][64];                // gamma, beta, bias per chain
  __shared__ float reach[2][3][64];              // BFS reach (0/1)
  __shared__ float degs[64];
  __shared__ float corr[2][64];

  const int g = blockIdx.x, tid = threadIdx.x, nb = g * 64;

  // ---- phase 0: global -> LDS loads ----
  {
    const int r = tid >> 3, c0 = (tid & 7) * 8;
    const float4* asrc = (const float4*)&adj[(size_t)(nb + r) * 4096 + nb + c0];
    *(float4*)&Ab[r][c0]     = asrc[0];
    *(float4*)&Ab[r][c0 + 4] = asrc[1];
    if (c0 < 32) {
      const float4* fs = (const float4*)&feat_node[(size_t)(nb + r) * 32 + c0];
      *(float4*)&Xb[0][r][c0]     = fs[0];
      *(float4*)&Xb[0][r][c0 + 4] = fs[1];
    } else {
      const float4* es = (const float4*)&embed[(size_t)idx[nb + r] * 32 + (c0 - 32)];
      *(float4*)&Xb[0][r][c0]     = es[0];
      *(float4*)&Xb[0][r][c0 + 4] = es[1];
    }
  }
  {
    const int base = tid * 16;  // 512*16 = 8192 = 2*4096
    const float* src = (base < 4096) ? &w1[base] : &w2[base - 4096];
    float* dst = &Wb[0][0] + base;
#pragma unroll
    for (int u = 0; u < 4; ++u)
      *(float4*)&dst[u * 4] = *(const float4*)&src[u * 4];
  }
  if (tid < 384) {
    const int a = tid >> 6, h = tid & 63;
    const float* s6 = (a == 0) ? gamma1 : (a == 1) ? beta1 : (a == 2) ? b1
                    : (a == 3) ? gamma2 : (a == 4) ? beta2 : b2;
    prm[a / 3][a % 3][h] = s6[h];
  }
  __syncthreads();

  const int hl = head_ids[g] - nb, tl = tail_ids[g] - nb;

  // ---- phase 1: reach0/1 + degs (waves 0-2) || transform GEMM (all) ----
  if (tid < 128) {
    const int ch = tid >> 6, j = tid & 63;
    const int root = ch ? tl : hl;
    reach[ch][0][j] = (j == root) ? 1.f : 0.f;
    reach[ch][1][j] = (j == root || Ab[root][j] != 0.f) ? 1.f : 0.f;
  } else if (tid < 192) {
    const int i = tid & 63;
    float s = 0.f;
    for (int k = 0; k < 64; ++k) s += Ab[i][k];
    degs[i] = s;
  }
  {
    const int r = tid >> 3, c0 = (tid & 7) * 8;
    float acc[8] = {};
    for (int k = 0; k < 64; ++k) {
      const float a = Xb[0][r][k];
      const float4 t0 = *(const float4*)&transform[(size_t)k * 64 + c0];
      const float4 t1 = *(const float4*)&transform[(size_t)k * 64 + c0 + 4];
      acc[0] = fmaf(a, t0.x, acc[0]); acc[1] = fmaf(a, t0.y, acc[1]);
      acc[2] = fmaf(a, t0.z, acc[2]); acc[3] = fmaf(a, t0.w, acc[3]);
      acc[4] = fmaf(a, t1.x, acc[4]); acc[5] = fmaf(a, t1.y, acc[5]);
      acc[6] = fmaf(a, t1.z, acc[6]); acc[7] = fmaf(a, t1.w, acc[7]);
    }
    *(float4*)&featb[r][c0]     = make_float4(acc[0], acc[1], acc[2], acc[3]);
    *(float4*)&featb[r][c0 + 4] = make_float4(acc[4], acc[5], acc[6], acc[7]);
  }
  __syncthreads();

  // ---- phase 2: reach2 (2 waves) + S init + layer-0 write (all) ----
  if (tid < 128) {
    const int ch = tid >> 6, j = tid & 63;
    const int root = ch ? tl : hl;
    float v = (j == root) ? 1.f : 0.f;
    for (int k = 0; k < 64; ++k)
      if (reach[ch][1][k] != 0.f && Ab[k][j] != 0.f) v = 1.f;
    reach[ch][2][j] = v;
  }
  {
    const int r = tid >> 3, c0 = (tid & 7) * 8;
#pragma unroll
    for (int u = 0; u < 2; ++u) {
      const float4 v = *(const float4*)&featb[r][c0 + 4 * u];
      *(float4*)&Sb[0][r][c0 + 4 * u] = v;
      *(float4*)&Sb[1][r][c0 + 4 * u] = v;
      *(float4*)&out[(size_t)(nb + r) * 256 + c0 + 4 * u] = v;
    }
  }
  __syncthreads();

  // hop-loop thread mapping: (chain, row, column-quarter)
  const int ch = tid >> 8, t = tid & 255;
  const int i4 = t >> 2, q4 = t & 3, c0 = q4 * 16;
  const int qrow = ch ? hl : tl;   // chain0 (head state) queries tail feat
  const int r8 = tid >> 3, cc8 = (tid & 7) * 8;

  for (int hop = 2; hop >= 0; --hop) {
    // F (deferred layer write) + A (corr), both pure reads of Sb/featb
    if (hop != 2) {
      const int L = 2 - hop;
#pragma unroll
      for (int u = 0; u < 2; ++u) {
        const float4 a = *(const float4*)&Sb[0][r8][cc8 + 4 * u];
        const float4 b = *(const float4*)&Sb[1][r8][cc8 + 4 * u];
        *(float4*)&out[(size_t)(nb + r8) * 256 + (size_t)L * 64 + cc8 + 4 * u] =
            make_float4(a.x + b.x, a.y + b.y, a.z + b.z, a.w + b.w);
      }
    }
    {
      float s = 0.f;
#pragma unroll
      for (int u = 0; u < 4; ++u) {
        const float4 qv = *(const float4*)&featb[qrow][c0 + 4 * u];
        const float4 sv = *(const float4*)&Sb[ch][i4][c0 + 4 * u];
        s = fmaf(qv.x, sv.x, s); s = fmaf(qv.y, sv.y, s);
        s = fmaf(qv.z, sv.z, s); s = fmaf(qv.w, sv.w, s);
      }
      s += __shfl_xor(s, 1);
      s += __shfl_xor(s, 2);
      if (q4 == 0) corr[ch][i4] = fabsf(s);
    }
    __syncthreads();

    // B+C+D fused: masked weighted agg -> leaky/deg -> LN (in-register) -> +f*feat
    {
      float acc[16] = {};
      for (int j = 0; j < 64; ++j) {
        const float w = Ab[i4][j] * corr[ch][j];  // branch-free mask
        const float4 s0 = *(const float4*)&Sb[ch][j][c0];
        const float4 s1 = *(const float4*)&Sb[ch][j][c0 + 4];
        const float4 s2 = *(const float4*)&Sb[ch][j][c0 + 8];
        const float4 s3 = *(const float4*)&Sb[ch][j][c0 + 12];
        acc[0]  = fmaf(w, s0.x, acc[0]);  acc[1]  = fmaf(w, s0.y, acc[1]);
        acc[2]  = fmaf(w, s0.z, acc[2]);  acc[3]  = fmaf(w, s0.w, acc[3]);
        acc[4]  = fmaf(w, s1.x, acc[4]);  acc[5]  = fmaf(w, s1.y, acc[5]);
        acc[6]  = fmaf(w, s1.z, acc[6]);  acc[7]  = fmaf(w, s1.w, acc[7]);
        acc[8]  = fmaf(w, s2.x, acc[8]);  acc[9]  = fmaf(w, s2.y, acc[9]);
        acc[10] = fmaf(w, s2.z, acc[10]); acc[11] = fmaf(w, s2.w, acc[11]);
        acc[12] = fmaf(w, s3.x, acc[12]); acc[13] = fmaf(w, s3.y, acc[13]);
        acc[14] = fmaf(w, s3.z, acc[14]); acc[15] = fmaf(w, s3.w, acc[15]);
      }
      const float dn = 1.f / (degs[i4] + 1e-8f);
      float x[16], sm = 0.f, s2m = 0.f;
#pragma unroll
      for (int c = 0; c < 16; ++c) {
        float z = acc[c];
        z = (z > 0.f) ? z : 0.01f * z;    // leaky_relu slope 0.01
        z *= dn;
        x[c] = z; sm += z; s2m = fmaf(z, z, s2m);
      }
      sm  += __shfl_xor(sm, 1);  sm  += __shfl_xor(sm, 2);
      s2m += __shfl_xor(s2m, 1); s2m += __shfl_xor(s2m, 2);
      const float mu = sm * 0.015625f;
      const float var = fmaxf(s2m * 0.015625f - mu * mu, 0.f);
      const float rstd = rsqrtf(var + 1e-5f);
      const float f = reach[ch][hop][i4];
#pragma unroll
      for (int c = 0; c < 16; ++c) {
        const int cc = c0 + c;
        x[c] = fmaf(f, featb[i4][cc],
                    prm[ch][0][cc] * (x[c] - mu) * rstd + prm[ch][1][cc]);
      }
#pragma unroll
      for (int u = 0; u < 4; ++u)
        *(float4*)&Xb[ch][i4][c0 + 4 * u] =
            make_float4(x[4*u], x[4*u+1], x[4*u+2], x[4*u+3]);
    }
    __syncthreads();

    // E: S[i] = f ? relu(X[i] @ W + b) : S[i]   (W from LDS)
    {
      float acc[16];
#pragma unroll
      for (int c = 0; c < 16; ++c) acc[c] = prm[ch][2][c0 + c];
      const float* Wl = Wb[ch];
      for (int k = 0; k < 64; ++k) {
        const float xv = Xb[ch][i4][k];
        const float4 w0 = *(const float4*)&Wl[k * 64 + c0];
        const float4 w1v = *(const float4*)&Wl[k * 64 + c0 + 4];
        const float4 w2v = *(const float4*)&Wl[k * 64 + c0 + 8];
        const float4 w3v = *(const float4*)&Wl[k * 64 + c0 + 12];
        acc[0]  = fmaf(xv, w0.x,  acc[0]);  acc[1]  = fmaf(xv, w0.y,  acc[1]);
        acc[2]  = fmaf(xv, w0.z,  acc[2]);  acc[3]  = fmaf(xv, w0.w,  acc[3]);
        acc[4]  = fmaf(xv, w1v.x, acc[4]);  acc[5]  = fmaf(xv, w1v.y, acc[5]);
        acc[6]  = fmaf(xv, w1v.z, acc[6]);  acc[7]  = fmaf(xv, w1v.w, acc[7]);
        acc[8]  = fmaf(xv, w2v.x, acc[8]);  acc[9]  = fmaf(xv, w2v.y, acc[9]);
        acc[10] = fmaf(xv, w2v.z, acc[10]); acc[11] = fmaf(xv, w2v.w, acc[11]);
        acc[12] = fmaf(xv, w3v.x, acc[12]); acc[13] = fmaf(xv, w3v.y, acc[13]);
        acc[14] = fmaf(xv, w3v.z, acc[14]); acc[15] = fmaf(xv, w3v.w, acc[15]);
      }
      if (reach[ch][hop][i4] != 0.f) {
#pragma unroll
        for (int u = 0; u < 4; ++u)
          *(float4*)&Sb[ch][i4][c0 + 4 * u] = make_float4(
              fmaxf(acc[4*u], 0.f),   fmaxf(acc[4*u+1], 0.f),
              fmaxf(acc[4*u+2], 0.f), fmaxf(acc[4*u+3], 0.f));
      }
    }
    __syncthreads();
  }

  // final layer 3 write
  {
#pragma unroll
    for (int u = 0; u < 2; ++u) {
      const float4 a = *(const float4*)&Sb[0][r8][cc8 + 4 * u];
      const float4 b = *(const float4*)&Sb[1][r8][cc8 + 4 * u];
      *(float4*)&out[(size_t)(nb + r8) * 256 + 192 + cc8 + 4 * u] =
          make_float4(a.x + b.x, a.y + b.y, a.z + b.z, a.w + b.w);
    }
  }
}

extern "C" void kernel_launch(void* const* d_in, const int* in_sizes, int n_in,
                              void* d_out, int out_size, void* d_ws, size_t ws_size,
                              hipStream_t stream) {
  const float* adj       = (const float*)d_in[0];
  const float* feat_node = (const float*)d_in[1];
  const int*   idx       = (const int*)d_in[2];
  const int*   head_ids  = (const int*)d_in[3];
  const int*   tail_ids  = (const int*)d_in[4];
  // d_in[5] = graph_indices (implied by block structure, unused)
  const float* transform = (const float*)d_in[6];
  const float* embed     = (const float*)d_in[7];
  const float* w1v    = (const float*)d_in[8];
  const float* b1v    = (const float*)d_in[9];
  const float* w2v    = (const float*)d_in[10];
  const float* b2v    = (const float*)d_in[11];
  const float* gamma1 = (const float*)d_in[12];
  const float* beta1  = (const float*)d_in[13];
  const float* gamma2 = (const float*)d_in[14];
  const float* beta2  = (const float*)d_in[15];

  lagat_kernel<<<64, 512, 0, stream>>>(adj, feat_node, idx, head_ids, tail_ids,
      transform, embed, w1v, b1v, w2v, b2v, gamma1, beta1, gamma2, beta2,
      (float*)d_out);
}